// Round 4
// baseline (400.741 us; speedup 1.0000x reference)
//
#include <hip/hip_runtime.h>

#define Bn   64
#define Tn   2048
#define ENCD 512
#define DECD 1024
#define HIDD 128
#define TT   32
#define NCH  (Tn / TT)       // 64 chunks per batch
#define CPG  8               // chunks per group (per block)
#define NGR  (NCH / CPG)     // 8 groups per batch
#define LROW 520             // bf16 elems per LDS row: 512 + 8 pad

typedef __attribute__((ext_vector_type(8))) short bf16x8;
typedef __attribute__((ext_vector_type(4))) float f32x4;

__device__ __forceinline__ unsigned short f2bf(float f) {
    union { float f; unsigned u; } v; v.f = f;
    unsigned r = v.u + 0x7FFFu + ((v.u >> 16) & 1u);   // RNE
    return (unsigned short)(r >> 16);
}
__device__ __forceinline__ float bf2f(unsigned short s) {
    union { unsigned u; float f; } v; v.u = ((unsigned)s) << 16;
    return v.f;
}
__device__ __forceinline__ float tanh_fast(float x) {
    float xa = fminf(fmaxf(x, -10.f), 10.f);
    float e = __expf(2.f * xa);
    return (e - 1.f) / (e + 1.f);
}

// ---------------------------------------------------------------------------
// Kernel 1: qb[b][h] = dec[b]·W_w[h] + V_b[h]   and   Vbf = bf16(V_w)
// grid = 512 (GEMV) + 64 (convert), block = 256
// ---------------------------------------------------------------------------
__global__ __launch_bounds__(256) void prep(
    const float* __restrict__ dec, const float* __restrict__ Ww,
    const float* __restrict__ Vb,  const float* __restrict__ Vw,
    float* __restrict__ qb, unsigned short* __restrict__ Vbf)
{
    const int blk = blockIdx.x, tid = threadIdx.x;
    if (blk < 512) {
        const int b = blk >> 3, hg = blk & 7;
        const int h_local = tid >> 4, seg = tid & 15;
        const int h = hg * 16 + h_local;
        const float4* w = (const float4*)(Ww + (size_t)h * DECD);
        const float4* d = (const float4*)(dec + (size_t)b * DECD);
        float acc = 0.f;
        #pragma unroll
        for (int j = 0; j < 16; ++j) {
            int f4 = j * 16 + seg;
            float4 a = d[f4], bb = w[f4];
            acc += a.x * bb.x + a.y * bb.y + a.z * bb.z + a.w * bb.w;
        }
        acc += __shfl_xor(acc, 1);
        acc += __shfl_xor(acc, 2);
        acc += __shfl_xor(acc, 4);
        acc += __shfl_xor(acc, 8);
        if (seg == 0) qb[b * HIDD + h] = acc + Vb[h];
    } else {
        // convert V_w (128x512 fp32 = 16384 float4) to bf16; 64 blocks x 256 f4
        const int c = blk - 512;
        const float4* src = (const float4*)Vw;
        int f4 = c * 256 + tid;
        float4 v = src[f4];
        ushort4 u;
        u.x = f2bf(v.x); u.y = f2bf(v.y); u.z = f2bf(v.z); u.w = f2bf(v.w);
        *(ushort4*)&Vbf[f4 * 4] = u;
    }
}

// ---------------------------------------------------------------------------
// Kernel 2: persistent, double-buffered, de-serialized.
// grid = (NGR, Bn) = (8, 64) = 512 blocks, block = 512 (8 waves).
// No-max softmax (scores bounded by ~11.4 -> exp() safe in fp32):
//   - no max reduction, no online rescale, no mC/gm
//   - every wave computes p[t] redundantly from wpart (no wave0 serialization)
//   - mask folded into an LDS bias preloaded once per block
// 2 barriers per chunk.
// ---------------------------------------------------------------------------
__global__ __launch_bounds__(512, 4) void attn_main(
    const float* __restrict__ enc, const int* __restrict__ mask,
    const float* __restrict__ qb,  const unsigned short* __restrict__ Vbf,
    const float* __restrict__ ww,  const float* __restrict__ wb,
    float* __restrict__ pW, float* __restrict__ lC, float* __restrict__ ctxG)
{
    __shared__ unsigned short encS[2 * TT * LROW];   // 66560 B (double buffer)
    __shared__ float wpart[8][TT];                   // 1024 B
    __shared__ float maskB[CPG * TT];                // 1024 B  (bias: -inf or wb)

    const int cg = blockIdx.x, b = blockIdx.y;
    const int tid = threadIdx.x;
    const int wave = tid >> 6, lane = tid & 63;
    const int li = lane & 15, quad = lane >> 4;

    // per-wave h column, loaded once
    const int h = wave * 16 + li;
    const float qv = qb[b * HIDD + h];
    const float wv = ww[h];
    const unsigned short* vrow = Vbf + (size_t)h * ENCD;

    const float4* encBase =
        (const float4*)(enc + ((size_t)b * Tn + (size_t)cg * (CPG * TT)) * ENCD);

    // mask bias preload (also folds in the scalar bias wb)
    if (tid < CPG * TT) {
        int mk = mask[b * Tn + cg * (CPG * TT) + tid];
        maskB[tid] = mk ? -INFINITY : wb[0];
    }

    float4 v[8];
    // ---- prologue: stage tile 0 ----
    #pragma unroll
    for (int it = 0; it < 8; ++it) v[it] = encBase[it * 512 + tid];
    #pragma unroll
    for (int it = 0; it < 8; ++it) {
        int f4 = it * 512 + tid;
        int t = f4 >> 7, e2 = (f4 & 127) * 4;
        ushort4 u;
        u.x = f2bf(v[it].x); u.y = f2bf(v[it].y);
        u.z = f2bf(v[it].z); u.w = f2bf(v[it].w);
        *(ushort4*)&encS[t * LROW + e2] = u;
    }
    __syncthreads();

    float ctx = 0.f;          // accumulated context for e = tid (no rescale)

    for (int i = 0; i < CPG; ++i) {
        unsigned short* sb = encS + (i & 1) * (TT * LROW);
        const int chunk = cg * CPG + i;

        // ---- MFMA: k[t, h] for this wave's 16 h, all 32 t ----
        f32x4 acc[2];
        acc[0] = (f32x4){0.f, 0.f, 0.f, 0.f};
        acc[1] = (f32x4){0.f, 0.f, 0.f, 0.f};
        #pragma unroll 4
        for (int ks = 0; ks < 16; ++ks) {
            int k0 = ks * 32 + quad * 8;
            bf16x8 a0 = *(const bf16x8*)&sb[(0  + li) * LROW + k0];
            bf16x8 a1 = *(const bf16x8*)&sb[(16 + li) * LROW + k0];
            bf16x8 bb = *(const bf16x8*)(vrow + k0);
            acc[0] = __builtin_amdgcn_mfma_f32_16x16x32_bf16(a0, bb, acc[0], 0, 0, 0);
            acc[1] = __builtin_amdgcn_mfma_f32_16x16x32_bf16(a1, bb, acc[1], 0, 0, 0);
        }

        // ---- prefetch next tile into regs (consumed at LDS store below) ----
        if (i + 1 < CPG) {
            #pragma unroll
            for (int it = 0; it < 8; ++it)
                v[it] = encBase[(i + 1) * (TT * ENCD / 4) + it * 512 + tid];
        }

        // ---- epilogue: s = tanh(k + q)*w_w; reduce over the wave's 16 h ----
        #pragma unroll
        for (int mt = 0; mt < 2; ++mt)
            #pragma unroll
            for (int r = 0; r < 4; ++r) {
                float s = tanh_fast(acc[mt][r] + qv) * wv;
                s += __shfl_xor(s, 1);
                s += __shfl_xor(s, 2);
                s += __shfl_xor(s, 4);
                s += __shfl_xor(s, 8);
                if (li == 0) wpart[wave][mt * 16 + quad * 4 + r] = s;
            }
        __syncthreads();                         // A: wpart ready

        // ---- p-phase: every lane computes p for t = lane&31 ----
        {
            const int t = lane & 31;
            float es = maskB[i * TT + t];
            #pragma unroll
            for (int w = 0; w < 8; ++w) es += wpart[w][t];
            float p = __expf(es);                // es <= ~11.4, no overflow

            if (wave == 0) {
                if (lane < TT)
                    pW[(size_t)b * Tn + chunk * TT + lane] = p;
                float ls = p;
                ls += __shfl_xor(ls, 1);
                ls += __shfl_xor(ls, 2);
                ls += __shfl_xor(ls, 4);
                ls += __shfl_xor(ls, 8);
                ls += __shfl_xor(ls, 16);
                if (lane == 0) lC[b * NCH + chunk] = ls;
            }

            // ---- context accumulation: e = tid, p broadcast via shfl ----
            #pragma unroll
            for (int t2 = 0; t2 < TT; ++t2)
                ctx += __shfl(p, t2) * bf2f(sb[t2 * LROW + tid]);
        }

        // ---- write next tile into the alternate LDS buffer ----
        if (i + 1 < CPG) {
            unsigned short* nb = encS + ((i + 1) & 1) * (TT * LROW);
            #pragma unroll
            for (int it = 0; it < 8; ++it) {
                int f4 = it * 512 + tid;
                int t = f4 >> 7, e2 = (f4 & 127) * 4;
                ushort4 u;
                u.x = f2bf(v[it].x); u.y = f2bf(v[it].y);
                u.z = f2bf(v[it].z); u.w = f2bf(v[it].w);
                *(ushort4*)&nb[t * LROW + e2] = u;
            }
        }
        __syncthreads();                         // B: nb ready / sb consumed
    }

    // one context partial per block (group)
    ctxG[((size_t)(b * NGR + cg)) * ENCD + tid] = ctx;
}

// ---------------------------------------------------------------------------
// Kernel 3: combine.  grid = (Bn, 2), block = 512
//   part 0: context (512 e, sum over 8 group partials, * 1/L)
//   part 1: weights (2048 t, * 1/L)
// ---------------------------------------------------------------------------
__global__ __launch_bounds__(512) void finalize(
    const float* __restrict__ lC, const float* __restrict__ pW,
    const float* __restrict__ ctxG, float* __restrict__ out)
{
    __shared__ float invLs;
    const int b = blockIdx.x, part = blockIdx.y, tid = threadIdx.x;
    const int wave = tid >> 6, lane = tid & 63;

    if (wave == 0) {                             // NCH == 64 == wave width
        float l = lC[b * NCH + lane];
        #pragma unroll
        for (int off = 32; off >= 1; off >>= 1)
            l += __shfl_xor(l, off);
        if (lane == 0) invLs = 1.f / l;
    }
    __syncthreads();
    const float invL = invLs;

    if (part == 0) {
        float c = 0.f;
        #pragma unroll
        for (int g = 0; g < NGR; ++g)
            c += ctxG[((size_t)(b * NGR + g)) * ENCD + tid];
        out[b * ENCD + tid] = c * invL;
    } else {
        float* outw = out + Bn * ENCD;
        #pragma unroll
        for (int i = 0; i < 4; ++i) {
            int t = i * 512 + tid;
            outw[(size_t)b * Tn + t] = pW[(size_t)b * Tn + t] * invL;
        }
    }
}

// ---------------------------------------------------------------------------
extern "C" void kernel_launch(void* const* d_in, const int* in_sizes, int n_in,
                              void* d_out, int out_size, void* d_ws, size_t ws_size,
                              hipStream_t stream)
{
    const float* enc  = (const float*)d_in[0];
    const float* dec  = (const float*)d_in[1];
    const int*   mask = (const int*)d_in[2];
    const float* Vw   = (const float*)d_in[3];
    const float* Vb   = (const float*)d_in[4];
    const float* Ww   = (const float*)d_in[5];
    const float* ww   = (const float*)d_in[6];
    const float* wb   = (const float*)d_in[7];
    float* out = (float*)d_out;
    float* ws  = (float*)d_ws;

    // ws layout (float offsets) — Vbf is 65536 bf16 = 131072 B = 32768 floats:
    float*          qb   = ws;                               //      0 ..   8192
    unsigned short* Vbf  = (unsigned short*)(ws + 8192);     //   8192 ..  40960
    float*          pW   = ws + 40960;                       //  40960 .. 172032
    float*          lC   = ws + 172032;                      // 172032 .. 176128
    float*          ctxG = ws + 176128;                      // 176128 .. 438272 (~1.75 MB)

    hipLaunchKernelGGL(prep, dim3(576), dim3(256), 0, stream, dec, Ww, Vb, Vw, qb, Vbf);
    hipLaunchKernelGGL(attn_main, dim3(NGR, Bn), dim3(512), 0, stream,
                       enc, mask, qb, Vbf, ww, wb, pW, lC, ctxG);
    hipLaunchKernelGGL(finalize, dim3(Bn, 2), dim3(512), 0, stream, lC, pW, ctxG, out);
}

// Round 5
// 391.176 us; speedup vs baseline: 1.0245x; 1.0245x over previous
//
#include <hip/hip_runtime.h>

#define Bn   64
#define Tn   2048
#define ENCD 512
#define DECD 1024
#define HIDD 128
#define TT   32
#define NCH  (Tn / TT)       // 64 chunks per batch
#define LROW 520             // bf16 elems per LDS row: 512 + 8 pad

typedef __attribute__((ext_vector_type(8))) short bf16x8;
typedef __attribute__((ext_vector_type(4))) float f32x4;

__device__ __forceinline__ unsigned short f2bf(float f) {
    union { float f; unsigned u; } v; v.f = f;
    unsigned r = v.u + 0x7FFFu + ((v.u >> 16) & 1u);   // RNE
    return (unsigned short)(r >> 16);
}
__device__ __forceinline__ float bf2f(unsigned short s) {
    union { unsigned u; float f; } v; v.u = ((unsigned)s) << 16;
    return v.f;
}
__device__ __forceinline__ float tanh_fast(float x) {
    float xa = fminf(fmaxf(x, -10.f), 10.f);
    float e = __expf(2.f * xa);
    return (e - 1.f) / (e + 1.f);
}

// ---------------------------------------------------------------------------
// Kernel 1: qb[b][h] = dec[b]·W_w[h] + V_b[h]   and   Vbf = bf16(V_w)
// grid = 512 (GEMV) + 64 (convert), block = 256
// ---------------------------------------------------------------------------
__global__ __launch_bounds__(256) void prep(
    const float* __restrict__ dec, const float* __restrict__ Ww,
    const float* __restrict__ Vb,  const float* __restrict__ Vw,
    float* __restrict__ qb, unsigned short* __restrict__ Vbf)
{
    const int blk = blockIdx.x, tid = threadIdx.x;
    if (blk < 512) {
        const int b = blk >> 3, hg = blk & 7;
        const int h_local = tid >> 4, seg = tid & 15;
        const int h = hg * 16 + h_local;
        const float4* w = (const float4*)(Ww + (size_t)h * DECD);
        const float4* d = (const float4*)(dec + (size_t)b * DECD);
        float acc = 0.f;
        #pragma unroll
        for (int j = 0; j < 16; ++j) {
            int f4 = j * 16 + seg;
            float4 a = d[f4], bb = w[f4];
            acc += a.x * bb.x + a.y * bb.y + a.z * bb.z + a.w * bb.w;
        }
        acc += __shfl_xor(acc, 1);
        acc += __shfl_xor(acc, 2);
        acc += __shfl_xor(acc, 4);
        acc += __shfl_xor(acc, 8);
        if (seg == 0) qb[b * HIDD + h] = acc + Vb[h];
    } else {
        // convert V_w (128x512 fp32 = 16384 float4) to bf16; 64 blocks x 256 f4
        const int c = blk - 512;
        const float4* src = (const float4*)Vw;
        int f4 = c * 256 + tid;
        float4 v = src[f4];
        ushort4 u;
        u.x = f2bf(v.x); u.y = f2bf(v.y); u.z = f2bf(v.z); u.w = f2bf(v.w);
        *(ushort4*)&Vbf[f4 * 4] = u;
    }
}

// ---------------------------------------------------------------------------
// Kernel 2: one-shot fused scores + no-max softmax + partial context.
// grid = (NCH, Bn) = (64, 64) = 4096 blocks, block = 512 (8 waves).
// - 33 KB LDS -> 4 blocks/CU, 32 waves/CU.
// - no-max softmax (|erg| <= ~11.4 -> exp safe in fp32): no max reduce.
// - all waves compute p redundantly from wpart: no wave0-serial phase,
//   only 2 barriers; ctx gets p via __shfl broadcast.
// - staging in 2 passes of 4 float4 -> 16 staging VGPRs, fits 64-VGPR budget.
// ---------------------------------------------------------------------------
__global__ __launch_bounds__(512, 8) void attn_main(
    const float* __restrict__ enc, const int* __restrict__ mask,
    const float* __restrict__ qb,  const unsigned short* __restrict__ Vbf,
    const float* __restrict__ ww,  const float* __restrict__ wb,
    float* __restrict__ pW, float* __restrict__ lC, float* __restrict__ ctxP)
{
    __shared__ unsigned short encS[TT * LROW];   // 33280 B
    __shared__ float wpart[8][TT];               // 1024 B

    const int chunk = blockIdx.x, b = blockIdx.y;
    const int tid = threadIdx.x;
    const int wave = tid >> 6, lane = tid & 63;
    const int li = lane & 15, quad = lane >> 4;
    const int t0 = chunk * TT;

    // early loads (overlap with staging): query, weight, mask bias
    const int h = wave * 16 + li;
    const float qv = qb[b * HIDD + h];
    const float wv = ww[h];
    const int tm = lane & 31;
    const float bias = (mask[b * Tn + t0 + tm] != 0) ? -INFINITY : wb[0];

    // ---- stage enc tile (16384 floats) -> bf16 LDS, 2 passes of 4 float4 ----
    const float4* encT4 = (const float4*)(enc + ((size_t)b * Tn + t0) * ENCD);
    #pragma unroll
    for (int half = 0; half < 2; ++half) {
        float4 v4[4];
        #pragma unroll
        for (int it = 0; it < 4; ++it)
            v4[it] = encT4[(half * 4 + it) * 512 + tid];
        #pragma unroll
        for (int it = 0; it < 4; ++it) {
            int f4 = (half * 4 + it) * 512 + tid;
            int t = f4 >> 7, e2 = (f4 & 127) * 4;
            ushort4 u;
            u.x = f2bf(v4[it].x); u.y = f2bf(v4[it].y);
            u.z = f2bf(v4[it].z); u.w = f2bf(v4[it].w);
            *(ushort4*)&encS[t * LROW + e2] = u;
        }
    }
    __syncthreads();

    // ---- MFMA: k[t, h] for this wave's 16 h, all 32 t ----
    f32x4 acc[2];
    acc[0] = (f32x4){0.f, 0.f, 0.f, 0.f};
    acc[1] = (f32x4){0.f, 0.f, 0.f, 0.f};
    const unsigned short* vrow = Vbf + (size_t)h * ENCD;

    #pragma unroll 4
    for (int ks = 0; ks < 16; ++ks) {
        int k0 = ks * 32 + quad * 8;
        bf16x8 a0 = *(const bf16x8*)&encS[(0  + li) * LROW + k0];
        bf16x8 a1 = *(const bf16x8*)&encS[(16 + li) * LROW + k0];
        bf16x8 bb = *(const bf16x8*)(vrow + k0);
        acc[0] = __builtin_amdgcn_mfma_f32_16x16x32_bf16(a0, bb, acc[0], 0, 0, 0);
        acc[1] = __builtin_amdgcn_mfma_f32_16x16x32_bf16(a1, bb, acc[1], 0, 0, 0);
    }

    // ---- epilogue: s = tanh(k + q)*w_w; reduce over the wave's 16 h ----
    #pragma unroll
    for (int mt = 0; mt < 2; ++mt)
        #pragma unroll
        for (int r = 0; r < 4; ++r) {
            float s = tanh_fast(acc[mt][r] + qv) * wv;
            s += __shfl_xor(s, 1);
            s += __shfl_xor(s, 2);
            s += __shfl_xor(s, 4);
            s += __shfl_xor(s, 8);
            if (li == 0) wpart[wave][mt * 16 + quad * 4 + r] = s;
        }
    __syncthreads();

    // ---- p-phase: every lane computes p for t = lane&31 (no max shift) ----
    float es = bias;
    #pragma unroll
    for (int w = 0; w < 8; ++w) es += wpart[w][tm];
    float p = __expf(es);                        // es <= ~11.4, no overflow

    if (wave == 0) {
        if (lane < TT)
            pW[(size_t)b * Tn + t0 + lane] = p;
        float ls = p;
        ls += __shfl_xor(ls, 1);
        ls += __shfl_xor(ls, 2);
        ls += __shfl_xor(ls, 4);
        ls += __shfl_xor(ls, 8);
        ls += __shfl_xor(ls, 16);
        if (lane == 0) lC[b * NCH + chunk] = ls;
    }

    // ---- partial context: ctx[e] = sum_t p[t]*enc[t][e], e = tid ----
    float c = 0.f;
    #pragma unroll
    for (int t2 = 0; t2 < TT; ++t2)
        c += __shfl(p, t2) * bf2f(encS[t2 * LROW + tid]);
    ctxP[((size_t)(b * NCH + chunk)) * ENCD + tid] = c;
}

// ---------------------------------------------------------------------------
// Kernel 3: combine.  grid = (Bn, 2), block = 512
//   part 0: context (512 e, sum over 64 chunk partials, * 1/L)
//   part 1: weights (2048 t, * 1/L)
// ---------------------------------------------------------------------------
__global__ __launch_bounds__(512) void finalize(
    const float* __restrict__ lC, const float* __restrict__ pW,
    const float* __restrict__ ctxP, float* __restrict__ out)
{
    __shared__ float invLs;
    const int b = blockIdx.x, part = blockIdx.y, tid = threadIdx.x;
    const int wave = tid >> 6, lane = tid & 63;

    if (wave == 0) {                             // NCH == 64 == wave width
        float l = lC[b * NCH + lane];
        #pragma unroll
        for (int off = 32; off >= 1; off >>= 1)
            l += __shfl_xor(l, off);
        if (lane == 0) invLs = 1.f / l;
    }
    __syncthreads();
    const float invL = invLs;

    if (part == 0) {
        float c = 0.f;
        #pragma unroll 16
        for (int cc = 0; cc < NCH; ++cc)
            c += ctxP[((size_t)(b * NCH + cc)) * ENCD + tid];
        out[b * ENCD + tid] = c * invL;
    } else {
        float* outw = out + Bn * ENCD;
        #pragma unroll
        for (int i = 0; i < 4; ++i) {
            int t = i * 512 + tid;
            outw[(size_t)b * Tn + t] = pW[(size_t)b * Tn + t] * invL;
        }
    }
}

// ---------------------------------------------------------------------------
extern "C" void kernel_launch(void* const* d_in, const int* in_sizes, int n_in,
                              void* d_out, int out_size, void* d_ws, size_t ws_size,
                              hipStream_t stream)
{
    const float* enc  = (const float*)d_in[0];
    const float* dec  = (const float*)d_in[1];
    const int*   mask = (const int*)d_in[2];
    const float* Vw   = (const float*)d_in[3];
    const float* Vb   = (const float*)d_in[4];
    const float* Ww   = (const float*)d_in[5];
    const float* ww   = (const float*)d_in[6];
    const float* wb   = (const float*)d_in[7];
    float* out = (float*)d_out;
    float* ws  = (float*)d_ws;

    // ws layout (float offsets) — Vbf is 65536 bf16 = 131072 B = 32768 floats:
    float*          qb   = ws;                               //      0 ..   8192
    unsigned short* Vbf  = (unsigned short*)(ws + 8192);     //   8192 ..  40960
    float*          pW   = ws + 40960;                       //  40960 .. 172032
    float*          lC   = ws + 172032;                      // 172032 .. 176128
    float*          ctxP = ws + 176128;                      // 176128 .. 2273280 (~9.1 MB)

    hipLaunchKernelGGL(prep, dim3(576), dim3(256), 0, stream, dec, Ww, Vb, Vw, qb, Vbf);
    hipLaunchKernelGGL(attn_main, dim3(NCH, Bn), dim3(512), 0, stream,
                       enc, mask, qb, Vbf, ww, wb, pW, lC, ctxP);
    hipLaunchKernelGGL(finalize, dim3(Bn, 2), dim3(512), 0, stream, lC, pW, ctxP, out);
}